// Round 1
// baseline (224.443 us; speedup 1.0000x reference)
//
#include <hip/hip_runtime.h>

// Problem dims (hardcoded from reference)
#define T_STEPS 256
#define B_ROWS  16384
#define IN_DIM  1024
#define C_CLS   10

typedef float vfloat4 __attribute__((ext_vector_type(4)));

// ---------------------------------------------------------------------------
// Kernel 1: xW = x @ W^T   ([B,IN] @ [C,IN]^T -> [B,C])
// 1024 blocks x 256 threads (4 waves). Each wave computes 4 rows over K=1024.
// x loads: float4, lane-contiguous -> fully coalesced (wave reads 1KB/instr).
// W loads: float4 per class per pass, 40KB total -> L1/L2 resident after warmup.
// ---------------------------------------------------------------------------
__global__ __launch_bounds__(256) void gemv_kernel(
    const float4* __restrict__ x4,   // [B][256] float4 view of x
    const float4* __restrict__ W4,   // [C][256] float4 view of W
    float* __restrict__ xw)          // [B][C]
{
    const int wave = threadIdx.x >> 6;
    const int lane = threadIdx.x & 63;
    const int row_base = blockIdx.x * 16 + wave * 4;

    float acc[4][C_CLS];
#pragma unroll
    for (int r = 0; r < 4; ++r)
#pragma unroll
        for (int c = 0; c < C_CLS; ++c) acc[r][c] = 0.0f;

#pragma unroll
    for (int p = 0; p < 4; ++p) {
        // load this pass's W fragment into registers (10 x float4 = 40 VGPR)
        float4 w[C_CLS];
#pragma unroll
        for (int c = 0; c < C_CLS; ++c)
            w[c] = W4[c * 256 + p * 64 + lane];

#pragma unroll
        for (int r = 0; r < 4; ++r) {
            float4 xv = x4[(size_t)(row_base + r) * 256 + p * 64 + lane];
#pragma unroll
            for (int c = 0; c < C_CLS; ++c) {
                acc[r][c] = fmaf(xv.x, w[c].x,
                            fmaf(xv.y, w[c].y,
                            fmaf(xv.z, w[c].z,
                            fmaf(xv.w, w[c].w, acc[r][c]))));
            }
        }
    }

    // 64-lane butterfly reduction for each of the 40 accumulators
#pragma unroll
    for (int r = 0; r < 4; ++r)
#pragma unroll
        for (int c = 0; c < C_CLS; ++c) {
            float v = acc[r][c];
#pragma unroll
            for (int off = 32; off >= 1; off >>= 1)
                v += __shfl_xor(v, off, 64);
            acc[r][c] = v;
        }

    if (lane == 0) {
#pragma unroll
        for (int r = 0; r < 4; ++r)
#pragma unroll
            for (int c = 0; c < C_CLS; ++c)
                xw[(row_base + r) * C_CLS + c] = acc[r][c];
    }
}

// ---------------------------------------------------------------------------
// Kernel 2: out[t,b,c] = coef(t) * xW[b,c]
//   coef(t) = 5 - 9*0.9^(t+1) + 4*0.8^(t+1)   (closed form of the LI scan)
// Fully coalesced float4 streaming writes; xW (655 KB) stays L2-resident.
// ---------------------------------------------------------------------------
__global__ __launch_bounds__(256) void expand_kernel(
    const float4* __restrict__ xw4,  // B*C/4 = 40960 float4
    float4* __restrict__ out4)       // T*B*C/4 = 10485760 float4
{
    const int SLICE4 = (B_ROWS * C_CLS) / 4;   // 40960 float4 per timestep
    const int TOTAL4 = T_STEPS * SLICE4;       // 10485760
    const float L9 = -0.15200309344504995f;    // log2(0.9)
    const float L8 = -0.32192809488736235f;    // log2(0.8)

    int idx = blockIdx.x * blockDim.x + threadIdx.x;
    const int stride = gridDim.x * blockDim.x;
    for (; idx < TOTAL4; idx += stride) {
        int t  = idx / SLICE4;
        int r4 = idx - t * SLICE4;
        float t1 = (float)(t + 1);
        float coef = 5.0f - 9.0f * exp2f(t1 * L9) + 4.0f * exp2f(t1 * L8);
        float4 v = xw4[r4];
        vfloat4 o;
        o.x = v.x * coef; o.y = v.y * coef; o.z = v.z * coef; o.w = v.w * coef;
        __builtin_nontemporal_store(o, (vfloat4*)(out4 + idx));
    }
}

extern "C" void kernel_launch(void* const* d_in, const int* in_sizes, int n_in,
                              void* d_out, int out_size, void* d_ws, size_t ws_size,
                              hipStream_t stream) {
    const float* x = (const float*)d_in[0];   // [B, IN] f32
    const float* W = (const float*)d_in[1];   // [C, IN] f32
    float* out = (float*)d_out;               // [T, B, C] f32
    float* xw  = (float*)d_ws;                // [B, C] f32 scratch (655 KB)

    gemv_kernel<<<B_ROWS / 16, 256, 0, stream>>>(
        (const float4*)x, (const float4*)W, xw);

    expand_kernel<<<2048, 256, 0, stream>>>(
        (const float4*)xw, (float4*)out);
}